// Round 5
// baseline (3761.814 us; speedup 1.0000x reference)
//
#include <hip/hip_runtime.h>
#include <math.h>

#define BB 512   // batch
#define TT 2048  // timesteps
#define DD 64    // input dim
#define HH 66    // hidden
#define GG 264   // 4*HH gates
#define GP 272   // padded gates (17 mfma n-tiles of 16), tr row stride
#define NTILE 17
#define NSUB 128 // 128 subchunks x 16 steps = 2048

typedef __attribute__((ext_vector_type(8))) __bf16 bf8_t;
typedef __attribute__((ext_vector_type(8))) unsigned short us8_t;
typedef __attribute__((ext_vector_type(4))) float f4_t;

__device__ __forceinline__ float fast_sigmoid(float x) {
  float e = __expf(-x);
  return __fdividef(1.0f, 1.0f + e);
}
__device__ __forceinline__ float fast_tanh(float x) {
  float e = __expf(2.0f * x);
  return 1.0f - __fdividef(2.0f, e + 1.0f);
}
__device__ __forceinline__ unsigned short f2bf(float f) {
  unsigned u = __builtin_bit_cast(unsigned, f);
  unsigned r = (u + 0x7fffu + ((u >> 16) & 1u)) >> 16;
  return (unsigned short)r;
}
__device__ __forceinline__ float bf2f(unsigned short h) {
  unsigned u = ((unsigned)h) << 16;
  return __builtin_bit_cast(float, u);
}
static __device__ __forceinline__ bf8_t as_bf8(us8_t u) {
  union { us8_t u; bf8_t b; } v; v.u = u; return v.b;
}
__device__ __forceinline__ void pack_hilo(float4 p0, float4 p1, us8_t& hi, us8_t& lo) {
  float v[8] = {p0.x, p0.y, p0.z, p0.w, p1.x, p1.y, p1.z, p1.w};
#pragma unroll
  for (int i = 0; i < 8; ++i) {
    unsigned short h = f2bf(v[i]);
    hi[i] = h;
    lo[i] = f2bf(v[i] - bf2f(h));
  }
}

// R8 (1-wave-per-sequence): lane j owns cell j. 5 W_hh rows per lane as
// NAMED scalars (SSA, not arrays -> no scratch; R1/R2 lesson):
//   wa/wb/wc/wd = rows q*66+j (q=0..3: i,f,g,o of cell j), j = lane 0..63
//   wx = one of the 8 leftover rows {64,65,130,131,196,197,262,263}
//        (cells 64,65 x 4 types), held by lanes 0..7 (one row each).
#define L66(X) \
  X(0) X(1) X(2) X(3) X(4) X(5) X(6) X(7) X(8) X(9) \
  X(10) X(11) X(12) X(13) X(14) X(15) X(16) X(17) X(18) X(19) \
  X(20) X(21) X(22) X(23) X(24) X(25) X(26) X(27) X(28) X(29) \
  X(30) X(31) X(32) X(33) X(34) X(35) X(36) X(37) X(38) X(39) \
  X(40) X(41) X(42) X(43) X(44) X(45) X(46) X(47) X(48) X(49) \
  X(50) X(51) X(52) X(53) X(54) X(55) X(56) X(57) X(58) X(59) \
  X(60) X(61) X(62) X(63) X(64) X(65)

#define L16A(X) X(0) X(1) X(2) X(3) X(4) X(5) X(6) X(7) X(8) X(9) X(10) X(11) X(12) X(13) X(14) X(15)
#define L16B(X) X(16) X(17) X(18) X(19) X(20) X(21) X(22) X(23) X(24) X(25) X(26) X(27) X(28) X(29) X(30) X(31)
#define L16C(X) X(32) X(33) X(34) X(35) X(36) X(37) X(38) X(39) X(40) X(41) X(42) X(43) X(44) X(45) X(46) X(47)
#define L16D(X) X(48) X(49) X(50) X(51) X(52) X(53) X(54) X(55) X(56) X(57) X(58) X(59) X(60) X(61) X(62) X(63)

#define DECLW(i) float wa##i, wb##i, wc##i, wd##i, wx##i;
#define LOADW(i) wa##i = pa[(i)]; wb##i = pb[(i)]; wc##i = pc[(i)]; wd##i = pd[(i)]; wx##i = pxw[(i)];

// Batched readlane (R2/R4 lesson: batch 16 rdl, THEN the fmas - first fma
// reads an SGPR written 16 instrs earlier, no VALU->SGPR->VALU wait states).
// h source = own register h_ (lane j holds h[j]); h64/h65 are wave-uniform
// VGPRs, no rdl needed for those two columns.
#define RDLH(i) const float hk##i = __builtin_bit_cast(float, __builtin_amdgcn_readlane(hsrc, (i)));
#define MAC5(i)                              \
  acc0 = fmaf(hk##i, wa##i, acc0);           \
  acc1 = fmaf(hk##i, wb##i, acc1);           \
  acc2 = fmaf(hk##i, wc##i, acc2);           \
  acc3 = fmaf(hk##i, wd##i, acc3);           \
  accx = fmaf(hk##i, wx##i, accx);
#define MAC5U(i, hv)                         \
  acc0 = fmaf((hv), wa##i, acc0);            \
  acc1 = fmaf((hv), wb##i, acc1);            \
  acc2 = fmaf((hv), wc##i, acc2);            \
  acc3 = fmaf((hv), wd##i, acc3);            \
  accx = fmaf((hv), wx##i, accx);

// Kernel 0: W_ih fp32 -> bf16 hi/lo, PERMUTED to cell-major row order
// r' = 4*cell + type  (<- src row type*66+cell), padded to 272 rows.
// Leftover rows land at r' = 256..263 = (cell 64|65, type 0..3) -> tr cols
// 256+k line up with the wx mapping below.
__global__ void conv_w(const float* __restrict__ W_ih,
                       unsigned short* __restrict__ hi,
                       unsigned short* __restrict__ lo) {
  int i = blockIdx.x * 256 + threadIdx.x;
  if (i >= GP * DD) return;
  int n = i >> 6, d = i & 63;
  float w = 0.0f;
  if (n < GG) {
    int c = n >> 2, t = n & 3;
    w = W_ih[(t * HH + c) * DD + d];
  }
  unsigned short h = f2bf(w);
  hi[i] = h;
  lo[i] = f2bf(w - bf2f(h));
}

// R8: ONE WAVE per sequence. Zero barriers, zero cross-wave exchange:
// - matvec: 64 batched rdl from own h + 5x66 fma (4 own rows + 1 leftover)
// - cell update in-lane; cells 64/65 gathered via 8 rdl, updated uniformly
// - x-projection: same hi/lo MFMA, done by this wave every 16 steps into
//   wave-private LDS tr (same-wave DS ordering -> no barrier needed).
// Grid 512 x 64: 2 waves/CU on separate SIMDs (VGPR ~440 -> 1 wave/SIMD).
__global__ __launch_bounds__(64, 1) void lstm_seq(
    const float* __restrict__ x,      // [B,T,D]
    const float* __restrict__ W_hh,   // [264,66] type-major rows
    const float* __restrict__ b_ih,   // [264]
    const float* __restrict__ b_hh,   // [264]
    const unsigned short* __restrict__ WbHi,  // [272,64] bf16, cell-major rows
    const unsigned short* __restrict__ WbLo,  // [272,64] bf16
    float* __restrict__ hT)           // [66,512]
{
  __shared__ __align__(16) float tr[16 * GP];  // 17408 B, wave-private

  const int b = blockIdx.x;
  const int l = threadIdx.x;        // lane 0..63 == cell index
  const int mlane = l & 15;
  const int quad = l >> 4;
  const int xk = l & 7;                              // leftover-row slot
  const int xr = (xk & 3) * HH + 64 + (xk >> 2);     // leftover W_hh row
  const bool isxtanh = ((xk & 3) == 2);

  // 330 named weight scalars.
  L66(DECLW)
  {
    const float* pa = W_hh + (0 * HH + l) * HH;
    const float* pb = W_hh + (1 * HH + l) * HH;
    const float* pc = W_hh + (2 * HH + l) * HH;
    const float* pd = W_hh + (3 * HH + l) * HH;
    const float* pxw = W_hh + xr * HH;
    L66(LOADW)
  }
  const float biasA = b_ih[0 * HH + l] + b_hh[0 * HH + l];
  const float biasB = b_ih[1 * HH + l] + b_hh[1 * HH + l];
  const float biasC = b_ih[2 * HH + l] + b_hh[2 * HH + l];
  const float biasD = b_ih[3 * HH + l] + b_hh[3 * HH + l];
  const float biasX = b_ih[xr] + b_hh[xr];

  float c_ = 0.0f, h_ = 0.0f;            // lane's own cell
  float c64 = 0.0f, c65 = 0.0f;          // wave-uniform extras
  float h64v = 0.0f, h65v = 0.0f;

  for (int sc = 0; sc < NSUB; ++sc) {
    // ---- x-projection (bf16 hi/lo MFMA) for the next 16 steps ----
    {
      const float* src = x + ((size_t)b * TT + sc * 16 + mlane) * DD;
      float4 a00 = *(const float4*)(src + quad * 8);
      float4 a01 = *(const float4*)(src + quad * 8 + 4);
      float4 a10 = *(const float4*)(src + 32 + quad * 8);
      float4 a11 = *(const float4*)(src + 32 + quad * 8 + 4);
      us8_t ah0, al0, ah1, al1;
      pack_hilo(a00, a01, ah0, al0);
      pack_hilo(a10, a11, ah1, al1);
      // unroll 2: bounded B-frag VGPR pressure (330 persistent regs live).
#pragma unroll 2
      for (int ti = 0; ti < NTILE; ++ti) {
        int n = ti * 16 + mlane;
        const us8_t* bh = (const us8_t*)(WbHi + n * DD + quad * 8);
        const us8_t* bl = (const us8_t*)(WbLo + n * DD + quad * 8);
        us8_t bh0 = bh[0], bh1 = bh[4];
        us8_t bl0 = bl[0], bl1 = bl[4];
        f4_t acc = {0.0f, 0.0f, 0.0f, 0.0f};
        acc = __builtin_amdgcn_mfma_f32_16x16x32_bf16(as_bf8(ah0), as_bf8(bh0), acc, 0, 0, 0);
        acc = __builtin_amdgcn_mfma_f32_16x16x32_bf16(as_bf8(ah1), as_bf8(bh1), acc, 0, 0, 0);
        acc = __builtin_amdgcn_mfma_f32_16x16x32_bf16(as_bf8(al0), as_bf8(bh0), acc, 0, 0, 0);
        acc = __builtin_amdgcn_mfma_f32_16x16x32_bf16(as_bf8(al1), as_bf8(bh1), acc, 0, 0, 0);
        acc = __builtin_amdgcn_mfma_f32_16x16x32_bf16(as_bf8(ah0), as_bf8(bl0), acc, 0, 0, 0);
        acc = __builtin_amdgcn_mfma_f32_16x16x32_bf16(as_bf8(ah1), as_bf8(bl1), acc, 0, 0, 0);
#pragma unroll
        for (int r = 0; r < 4; ++r) tr[(quad * 4 + r) * GP + n] = acc[r];
      }
    }
    // no barrier: same-wave DS ops are in-order (lgkmcnt).

    for (int s = 0; s < 16; ++s) {
      // x_proj + bias for this lane's 4 gates (cell-major cols 4l..4l+3)
      float4 p4 = *(const float4*)&tr[s * GP + 4 * l];
      float pxv = tr[s * GP + 256 + xk];  // leftover row's x_proj (bcast)
      float acc0 = p4.x + biasA;
      float acc1 = p4.y + biasB;
      float acc2 = p4.z + biasC;
      float acc3 = p4.w + biasD;
      float accx = pxv + biasX;
      const int hsrc = __builtin_bit_cast(int, h_);
      { L16A(RDLH) L16A(MAC5) }
      { L16B(RDLH) L16B(MAC5) }
      { L16C(RDLH) L16C(MAC5) }
      { L16D(RDLH) L16D(MAC5) }
      MAC5U(64, h64v)
      MAC5U(65, h65v)
      // own cell update (all in-lane)
      float iv = fast_sigmoid(acc0);
      float fv = fast_sigmoid(acc1);
      float gv = fast_tanh(acc2);
      float ov = fast_sigmoid(acc3);
      c_ = fmaf(fv, c_, iv * gv);
      h_ = ov * fast_tanh(c_);
      // cells 64/65: lanes 0..7 hold the 8 leftover pre-activations;
      // gather via rdl (uniform), update redundantly on all lanes.
      float sx = fast_sigmoid(accx);
      float tx = fast_tanh(accx);
      float ax = isxtanh ? tx : sx;
      const int axi = __builtin_bit_cast(int, ax);
      float i64 = __builtin_bit_cast(float, __builtin_amdgcn_readlane(axi, 0));
      float f64 = __builtin_bit_cast(float, __builtin_amdgcn_readlane(axi, 1));
      float g64 = __builtin_bit_cast(float, __builtin_amdgcn_readlane(axi, 2));
      float o64 = __builtin_bit_cast(float, __builtin_amdgcn_readlane(axi, 3));
      float i65 = __builtin_bit_cast(float, __builtin_amdgcn_readlane(axi, 4));
      float f65 = __builtin_bit_cast(float, __builtin_amdgcn_readlane(axi, 5));
      float g65 = __builtin_bit_cast(float, __builtin_amdgcn_readlane(axi, 6));
      float o65 = __builtin_bit_cast(float, __builtin_amdgcn_readlane(axi, 7));
      c64 = fmaf(f64, c64, i64 * g64);
      h64v = o64 * fast_tanh(c64);
      c65 = fmaf(f65, c65, i65 * g65);
      h65v = o65 * fast_tanh(c65);
    }
  }
  hT[l * BB + b] = h_;
  if (l == 0) {
    hT[64 * BB + b] = h64v;
    hT[65 * BB + b] = h65v;
  }
}

// BN batch-stats folded into final linear. Single block.
__global__ __launch_bounds__(512) void bn_fc(
    const float* __restrict__ hT, const float* __restrict__ gamma,
    const float* __restrict__ beta, const float* __restrict__ fc_w,
    const float* __restrict__ fc_b, float* __restrict__ out) {
  __shared__ float w2[HH];
  __shared__ float s2[HH];
  const int tid = threadIdx.x;
  const int wv = tid >> 6;
  const int lane = tid & 63;

  for (int j = wv; j < HH; j += 8) {
    const float* p = hT + j * BB;
    float s = 0.0f, ss = 0.0f;
#pragma unroll
    for (int m = 0; m < 8; ++m) {
      float v = p[lane + (m << 6)];
      s += v;
      ss = fmaf(v, v, ss);
    }
#pragma unroll
    for (int d = 32; d >= 1; d >>= 1) {
      s += __shfl_xor(s, d);
      ss += __shfl_xor(ss, d);
    }
    if (lane == 0) {
      float mean = s * (1.0f / BB);
      float var = ss * (1.0f / BB) - mean * mean;
      float scale = gamma[j] * rsqrtf(var + 1e-5f);
      float shift = beta[j] - mean * scale;
      float fw = fc_w[j];
      w2[j] = scale * fw;
      s2[j] = shift * fw;
    }
  }
  __syncthreads();

  float acc = 0.0f;
#pragma unroll
  for (int j = 0; j < HH; ++j) acc = fmaf(hT[j * BB + tid], w2[j], acc);
  float cst = fc_b[0];
#pragma unroll
  for (int j = 0; j < HH; ++j) cst += s2[j];
  out[tid] = acc + cst;
}

extern "C" void kernel_launch(void* const* d_in, const int* in_sizes, int n_in,
                              void* d_out, int out_size, void* d_ws, size_t ws_size,
                              hipStream_t stream) {
  const float* x     = (const float*)d_in[0];
  const float* W_ih  = (const float*)d_in[1];
  const float* W_hh  = (const float*)d_in[2];
  const float* b_ih  = (const float*)d_in[3];
  const float* b_hh  = (const float*)d_in[4];
  const float* gamma = (const float*)d_in[5];
  const float* beta  = (const float*)d_in[6];
  const float* fc_w  = (const float*)d_in[7];
  const float* fc_b  = (const float*)d_in[8];
  float* out = (float*)d_out;

  unsigned short* wbhi = (unsigned short*)d_ws;                  // 34816 B
  unsigned short* wblo = (unsigned short*)((char*)d_ws + 34816); // 34816 B
  float* hT            = (float*)((char*)d_ws + 69632);          // 135168 B

  conv_w<<<68, 256, 0, stream>>>(W_ih, wbhi, wblo);
  lstm_seq<<<BB, 64, 0, stream>>>(x, W_hh, b_ih, b_hh, wbhi, wblo, hT);
  bn_fc<<<1, 512, 0, stream>>>(hT, gamma, beta, fc_w, fc_b, out);
}